// Round 1
// baseline (13540.555 us; speedup 1.0000x reference)
//
#include <hip/hip_runtime.h>

#define HH 200   // hidden
#define GG 800   // 4*H gates
#define DD 24    // d_model
#define BB 64    // batch
#define TT 2048  // timesteps
#define CH 16    // timestep chunk for ux precompute (LDS-resident)
#define NT 832   // 13 waves per block

__device__ __forceinline__ float fsig(float x) {
    // 1/(1+e^-x); saturates cleanly at +-inf
    float e = __expf(-x);
    return 1.f / (1.f + e);
}
__device__ __forceinline__ float ftanh(float x) {
    // 1 - 2/(e^{2x}+1); e=inf -> 1, e=0 -> -1 (no NaN)
    float e = __expf(2.f * x);
    return 1.f - 2.f / (e + 1.f);
}

// Interleaved transpose: dst[(j/4)*(GG*4) + g*4 + (j%4)] = src[g*HH + j]
// so a gate-thread g reads 4 consecutive j weights as one coalesced float4.
__global__ void xpose(const float* __restrict__ src, float* __restrict__ dst) {
    int idx = blockIdx.x * blockDim.x + threadIdx.x;
    if (idx < GG * HH) {
        int g = idx / HH, j = idx % HH;
        dst[(size_t)(j >> 2) * (GG * 4) + g * 4 + (j & 3)] = src[idx];
    }
}

template <bool XP>
__global__ __launch_bounds__(NT)
void lstm_kernel(const float* __restrict__ emb,     // [B,T,D]
                 const float* __restrict__ h_past,  // [B,T,H]
                 const float* __restrict__ U_w,     // [4H,H]
                 const float* __restrict__ U_b,     // [4H]
                 const float* __restrict__ W_w,     // [4H,H]
                 const float* __restrict__ V_w,     // [H,D]
                 const float* __restrict__ V_b,     // [H]
                 const float* __restrict__ h0,      // [1,H]
                 const float* __restrict__ c0,      // [1,H]
                 const float* __restrict__ UT,      // transposed-interleaved U (if XP)
                 const float* __restrict__ WT,      // transposed-interleaved W (if XP)
                 float* __restrict__ out)           // [B,T,H]
{
    __shared__ float ux_sh[CH][GG];      // 51.2 KB: U(x) for chunk
    __shared__ float hp_sh[CH][HH];      // 12.8 KB: h_past chunk
    __shared__ float emb_sh[CH][DD];     //  1.5 KB
    __shared__ float h_sh[HH];           //  0.8 KB: recurrent h
    __shared__ float g_sh[GG];           //  3.2 KB: activated gates
    __shared__ float Vw_sh[HH][DD + 1];  // 20.0 KB (+1 pad: stride 25 is bank-clean)
    __shared__ float Vb_sh[HH];          //  0.8 KB

    const int tid = threadIdx.x;
    const int b = blockIdx.x;

    // one-time staging
    for (int i = tid; i < HH * DD; i += NT) Vw_sh[i / DD][i % DD] = V_w[i];
    if (tid < HH) { Vb_sh[tid] = V_b[tid]; h_sh[tid] = h0[tid]; }
    float c = (tid < HH) ? c0[tid] : 0.f;
    const float ub = (tid < GG) ? U_b[tid] : 0.f;

    const float* hpb  = h_past + (size_t)b * TT * HH;
    const float* embb = emb    + (size_t)b * TT * DD;
    float*       outb = out    + (size_t)b * TT * HH;

    __syncthreads();

    for (int t0 = 0; t0 < TT; t0 += CH) {
        // ---- stage this chunk's inputs (coalesced) ----
        for (int i = tid; i < CH * HH; i += NT)
            (&hp_sh[0][0])[i] = hpb[(size_t)t0 * HH + i];
        for (int i = tid; i < CH * DD; i += NT)
            (&emb_sh[0][0])[i] = embb[(size_t)t0 * DD + i];
        __syncthreads();

        // ---- ux = h_past @ U^T + U_b for CH steps (U streamed once per chunk) ----
        if (tid < GG) {
            float2 acc[CH];
            #pragma unroll
            for (int s = 0; s < CH; ++s) acc[s] = make_float2(0.f, 0.f);
            for (int j = 0; j < HH; j += 4) {
                float4 u4;
                if (XP) u4 = *(const float4*)(UT + (size_t)(j >> 2) * (GG * 4) + tid * 4);
                else    u4 = *(const float4*)(U_w + (size_t)tid * HH + j);
                #pragma unroll
                for (int s = 0; s < CH; ++s) {
                    float4 hp4 = *(const float4*)(&hp_sh[s][j]);   // wave-uniform broadcast
                    acc[s].x = fmaf(u4.x, hp4.x, acc[s].x);
                    acc[s].y = fmaf(u4.y, hp4.y, acc[s].y);
                    acc[s].x = fmaf(u4.z, hp4.z, acc[s].x);
                    acc[s].y = fmaf(u4.w, hp4.w, acc[s].y);
                }
            }
            #pragma unroll
            for (int s = 0; s < CH; ++s) ux_sh[s][tid] = acc[s].x + acc[s].y + ub;
        }
        __syncthreads();

        // ---- sequential recurrence over the chunk ----
        for (int s = 0; s < CH; ++s) {
            // ve for the update lanes (independent of gates; D=24 is cheap)
            float ve = 0.f;
            if (tid < HH) {
                float a = Vb_sh[tid];
                #pragma unroll
                for (int d = 0; d < DD; ++d)
                    a = fmaf(emb_sh[s][d], Vw_sh[tid][d], a);
                ve = ftanh(a);
            }
            // gate dot: one gate row per thread, W streamed from L2
            if (tid < GG) {
                float2 g2 = make_float2(0.f, 0.f);
                for (int j = 0; j < HH; j += 4) {
                    float4 w4;
                    if (XP) w4 = *(const float4*)(WT + (size_t)(j >> 2) * (GG * 4) + tid * 4);
                    else    w4 = *(const float4*)(W_w + (size_t)tid * HH + j);
                    float4 h4 = *(const float4*)(&h_sh[j]);        // wave-uniform broadcast
                    g2.x = fmaf(w4.x, h4.x, g2.x);
                    g2.y = fmaf(w4.y, h4.y, g2.y);
                    g2.x = fmaf(w4.z, h4.z, g2.x);
                    g2.y = fmaf(w4.w, h4.w, g2.y);
                }
                float gv = g2.x + g2.y + ux_sh[s][tid];
                bool isg = (tid >= 2 * HH) && (tid < 3 * HH);      // rows [400,600) = g-gate
                g_sh[tid] = isg ? ftanh(gv) : fsig(gv);
            }
            __syncthreads();   // gates ready; all h_sh reads done
            if (tid < HH) {
                float ig = g_sh[tid], fg = g_sh[HH + tid];
                float zg = g_sh[2 * HH + tid], og = g_sh[3 * HH + tid];
                c = fmaf(fg, c, ig * zg);
                float h = fmaf(og, ftanh(c), ve);
                h_sh[tid] = h;
                outb[(size_t)(t0 + s) * HH + tid] = h;
            }
            __syncthreads();   // h_sh updated, g_sh free
        }
    }
}

extern "C" void kernel_launch(void* const* d_in, const int* in_sizes, int n_in,
                              void* d_out, int out_size, void* d_ws, size_t ws_size,
                              hipStream_t stream) {
    const float* emb    = (const float*)d_in[0];
    const float* h_past = (const float*)d_in[1];
    const float* U_w    = (const float*)d_in[2];
    const float* U_b    = (const float*)d_in[3];
    const float* W_w    = (const float*)d_in[4];
    const float* V_w    = (const float*)d_in[5];
    const float* V_b    = (const float*)d_in[6];
    const float* h0     = (const float*)d_in[7];
    const float* c0     = (const float*)d_in[8];
    float* out = (float*)d_out;

    const size_t wneed = (size_t)2 * GG * HH * sizeof(float);  // 1.28 MB
    if (ws_size >= wneed) {
        float* UT = (float*)d_ws;
        float* WT = UT + (size_t)GG * HH;
        int nb = (GG * HH + 255) / 256;
        xpose<<<nb, 256, 0, stream>>>(U_w, UT);   // re-done every call: ws is re-poisoned
        xpose<<<nb, 256, 0, stream>>>(W_w, WT);
        lstm_kernel<true><<<BB, NT, 0, stream>>>(emb, h_past, U_w, U_b, W_w,
                                                 V_w, V_b, h0, c0, UT, WT, out);
    } else {
        lstm_kernel<false><<<BB, NT, 0, stream>>>(emb, h_past, U_w, U_b, W_w,
                                                  V_w, V_b, h0, c0, nullptr, nullptr, out);
    }
}